// Round 14
// baseline (33.538 us; speedup 1.0000x reference)
//
#include <hip/hip_runtime.h>

#define BSZ  8
#define LSEQ 2048
#define DM   256
#define NS   16
#define NC   32          // chunks along L
#define LC   (LSEQ/NC)   // 64 timesteps per chunk
#define DH   128         // d-half width: blocks split the d-dim in two
#define TPB  DH          // 128 threads = 2 waves
#define HALF_FLOATS (LC * DH)            // 32 KB LDS half-tile (k_final)

// ---------------------------------------------------------------------------
// Kernel 1: per-(b,chunk,d-half) local scan, h0=0; emit carry half.
// d-split: 512 blocks x 128 thr -> 2 independent blocks/CU whose
// stage/scan/store phases interleave (r13's occupancy test redone WITHOUT
// the 2x carry-traffic confound). Direct strided loads (LDS was neutral, r9).
// carry layout: [b][chunk][n][d]  (d contiguous -> coalesced)
// ---------------------------------------------------------------------------
__global__ void k_local(
        const float* __restrict__ x,
        const float* __restrict__ A,
        const float* __restrict__ Bm,
        const float* __restrict__ delta,
        float* __restrict__ carry) {
    const int i     = threadIdx.x;          // 0..127
    const int dh    = blockIdx.x & 1;
    const int chunk = (blockIdx.x >> 1) & (NC - 1);
    const int b     = blockIdx.x >> 6;      // 512 blocks / 64 = 8 batches
    const int d     = dh * DH + i;

    const float dt = 1.0f / (1.0f + expf(-delta[d]));
    float a[NS], bb[NS];
#pragma unroll
    for (int n = 0; n < NS; ++n) {
        a[n]  = expf(dt * A[d * NS + n]);
        bb[n] = dt * Bm[d * NS + n];
    }

    float h[NS];
#pragma unroll
    for (int n = 0; n < NS; ++n) h[n] = 0.0f;

    const float* xp = x + ((size_t)(b * LSEQ + chunk * LC)) * DM + d;
#pragma unroll 4
    for (int t = 0; t < LC; ++t) {
        const float xv = xp[(size_t)t * DM];
#pragma unroll
        for (int n = 0; n < NS; ++n) h[n] = fmaf(a[n], h[n], bb[n] * xv);
    }

    float* cp = carry + ((size_t)(b * NC + chunk) * NS) * DM + d;
#pragma unroll
    for (int n = 0; n < NS; ++n) cp[(size_t)n * DM] = h[n];
}

// ---------------------------------------------------------------------------
// Pass 2: per-(b,n,d) prefix over NC carries: load-all (independent, one
// memory round-trip) -> register chain -> store-all.  v[32] = 32 VGPRs,
// full unroll => static indices => registers (rule #20).
// ---------------------------------------------------------------------------
__global__ void k_prefix(
        const float* __restrict__ A,
        const float* __restrict__ delta,
        float* __restrict__ carry) {
    const int tid = blockIdx.x * 256 + threadIdx.x;   // 0 .. BSZ*NS*DM-1
    const int d = tid & (DM - 1);
    const int n = (tid >> 8) & (NS - 1);
    const int b = tid >> 12;

    const float dt = 1.0f / (1.0f + expf(-delta[d]));
    const float aL = expf(dt * A[d * NS + n] * (float)LC);

    float* cp = carry + (size_t)b * NC * NS * DM + (size_t)n * DM + d;

    float v[NC];
#pragma unroll
    for (int j = 0; j < NC; ++j) v[j] = cp[(size_t)j * NS * DM];

    float run = 0.0f;
#pragma unroll
    for (int j = 0; j < NC; ++j) {
        const float c = v[j];
        v[j] = run;                    // state entering chunk j
        run = fmaf(aL, run, c);        // state leaving chunk j
    }

#pragma unroll
    for (int j = 0; j < NC; ++j) cp[(size_t)j * NS * DM] = v[j];
}

// ---------------------------------------------------------------------------
// Kernel 3: seeded replay, d-split.  Entry-state loads issued first; x
// half-tile staged to LDS via float4 (512 B row-segments); scan from LDS
// (bank: (t*128+i)%32 = i%32 -> 2-way alias = free); y in place; float4 store.
// ---------------------------------------------------------------------------
__global__ void k_final(
        const float* __restrict__ x,
        const float* __restrict__ A,
        const float* __restrict__ Bm,
        const float* __restrict__ Cm,
        const float* __restrict__ Dv,
        const float* __restrict__ delta,
        const float* __restrict__ hin,
        float* __restrict__ y) {
    __shared__ float lt[HALF_FLOATS];
    const int i     = threadIdx.x;          // 0..127
    const int dh    = blockIdx.x & 1;
    const int chunk = (blockIdx.x >> 1) & (NC - 1);
    const int b     = blockIdx.x >> 6;
    const int d     = dh * DH + i;

    // entry state first: 16 strided loads in flight early
    float h[NS];
    const float* hp = hin + ((size_t)(b * NC + chunk) * NS) * DM + d;
#pragma unroll
    for (int n = 0; n < NS; ++n) h[n] = hp[(size_t)n * DM];

    const size_t tile_base = ((size_t)(b * LSEQ + chunk * LC)) * DM;
    const float* src_base = x + tile_base + dh * DH;   // row stride DM
    {   // stage half-tile: 16 rounds x 128 thr x 16 B = 32 KB
        float4* lt4 = (float4*)lt;
#pragma unroll
        for (int r = 0; r < 16; ++r) {
            const int t  = r * 4 + (i >> 5);
            const int c4 = i & 31;
            lt4[r * DH + i] =
                ((const float4*)(src_base + (size_t)t * DM))[c4];
        }
    }

    const float dt = 1.0f / (1.0f + expf(-delta[d]));
    float a[NS], bb[NS], cc[NS];
#pragma unroll
    for (int n = 0; n < NS; ++n) {
        a[n]  = expf(dt * A[d * NS + n]);
        bb[n] = dt * Bm[d * NS + n];
        cc[n] = Cm[d * NS + n];
    }
    const float Dd = Dv[d];
    __syncthreads();

#pragma unroll 4
    for (int t = 0; t < LC; ++t) {
        const float xv = lt[t * DH + i];
        float acc = Dd * xv;
#pragma unroll
        for (int n = 0; n < NS; ++n) {
            h[n] = fmaf(a[n], h[n], bb[n] * xv);
            acc  = fmaf(h[n], cc[n], acc);
        }
        lt[t * DH + i] = acc;          // slot (t,i) owned by thread i
    }
    __syncthreads();

    {   // vectorized store of the y half-tile
        float* dst_base = y + tile_base + dh * DH;
        const float4* lt4 = (const float4*)lt;
#pragma unroll
        for (int r = 0; r < 16; ++r) {
            const int t  = r * 4 + (i >> 5);
            const int c4 = i & 31;
            ((float4*)(dst_base + (size_t)t * DM))[c4] = lt4[r * DH + i];
        }
    }
}

// ---------------------------------------------------------------------------
extern "C" void kernel_launch(void* const* d_in, const int* in_sizes, int n_in,
                              void* d_out, int out_size, void* d_ws, size_t ws_size,
                              hipStream_t stream) {
    const float* x     = (const float*)d_in[0];
    const float* A     = (const float*)d_in[1];
    const float* Bm    = (const float*)d_in[2];
    const float* Cm    = (const float*)d_in[3];
    const float* Dv    = (const float*)d_in[4];
    const float* delta = (const float*)d_in[5];
    float* y = (float*)d_out;

    float* carry = (float*)d_ws;   // BSZ*NC*NS*DM*4 = 4.2 MiB scratch

    dim3 grd1(BSZ * NC * 2);             // 512 blocks x 128 thr, 2 blocks/CU
    k_local<<<grd1, dim3(TPB), 0, stream>>>(x, A, Bm, delta, carry);

    dim3 grd2((BSZ * NS * DM) / 256);    // 128 blocks
    k_prefix<<<grd2, dim3(256), 0, stream>>>(A, delta, carry);

    k_final<<<grd1, dim3(TPB), 0, stream>>>(x, A, Bm, Cm, Dv, delta, carry, y);
}